// Round 1
// baseline (2783.733 us; speedup 1.0000x reference)
//
#include <hip/hip_runtime.h>
#include <math.h>

// Problem constants
#define BATCH 8
#define CIN 16
#define HID 64
#define TT 4
#define S2 1024            // 32*32
#define SP 4096            // TT*S2 spatial elems per channel
#define CHB 262144         // HID*SP per batch
#define TAU 5
#define GATE_SZ 2097152    // BATCH*CHB = one gate buffer (floats)
#define EPS 1e-5f

// ws layout (floats): [0..3*GATE_SZ) = u4,u5,u6 ; [3*GATE_SZ) Z ; [4*GATE_SZ) stats(128)
#define WS_Z_OFF   ((size_t)3 * GATE_SZ)
#define WS_ST_OFF  ((size_t)4 * GATE_SZ)
// stats: scores[0..39] (l*8+b), attn[40..79], bsum[80..87], bsumsq[88..95]

__device__ __forceinline__ float* gate_ptr(float* out, float* ws, int g) {
    return (g < 4) ? (out + (size_t)g * GATE_SZ) : (ws + (size_t)(g - 4) * GATE_SZ);
}

// Accumulate one conv branch (nch input channels) for 4 t-planes at (y,xx).
__device__ __forceinline__ void conv_accum(const float* __restrict__ base,
                                           const float* __restrict__ wv_base,
                                           int nch, int y, int xx,
                                           float& a0, float& a1, float& a2, float& a3)
{
    for (int ic = 0; ic < nch; ++ic) {
        const float* p  = base + (size_t)ic * SP;
        const float* wv = wv_base + ic * 27;
        #pragma unroll
        for (int ky = 0; ky < 3; ++ky) {
            int yy = y + ky - 1;
            if ((unsigned)yy >= 32u) continue;
            #pragma unroll
            for (int kx = 0; kx < 3; ++kx) {
                int xv = xx + kx - 1;
                if ((unsigned)xv >= 32u) continue;
                const int off = yy * 32 + xv;
                const float v0 = p[off], v1 = p[S2 + off], v2 = p[2*S2 + off], v3 = p[3*S2 + off];
                const float w0 = wv[ky*3 + kx], w1 = wv[9 + ky*3 + kx], w2 = wv[18 + ky*3 + kx];
                a0 += v0*w1 + v1*w2;               // t=0: kd=1,2
                a1 += v0*w0 + v1*w1 + v2*w2;       // t=1
                a2 += v1*w0 + v2*w1 + v3*w2;       // t=2
                a3 += v2*w0 + v3*w1;               // t=3: kd=0,1
            }
        }
    }
}

// u_i = conv3d(x, Wx[i]) + conv3d(state_i, Wh[i]) + biases, i = 0..6
__global__ __launch_bounds__(1024) void conv_gates_k(
    const float* __restrict__ x, const float* __restrict__ h,
    const float* __restrict__ m, const float* __restrict__ Wx,
    const float* __restrict__ bx, const float* __restrict__ Wh,
    const float* __restrict__ bh, float* __restrict__ out, float* __restrict__ ws)
{
    const int blk = blockIdx.x;          // i*512 + b*64 + oc
    const int i   = blk >> 9;
    const int b   = (blk >> 6) & 7;
    const int oc  = blk & 63;
    const float* st = (i >= 3 && i <= 5) ? m : h;

    __shared__ float wl[(CIN + HID) * 27];
    {
        const float* wx = Wx + (size_t)(i * HID + oc) * (CIN * 27);
        const float* wh = Wh + (size_t)(i * HID + oc) * (HID * 27);
        for (int k = threadIdx.x; k < CIN * 27; k += 1024) wl[k] = wx[k];
        for (int k = threadIdx.x; k < HID * 27; k += 1024) wl[CIN * 27 + k] = wh[k];
    }
    __syncthreads();

    const int y  = threadIdx.x >> 5;
    const int xx = threadIdx.x & 31;
    const float bias = bx[i * HID + oc] + bh[i * HID + oc];
    float a0 = bias, a1 = bias, a2 = bias, a3 = bias;

    conv_accum(x  + (size_t)b * CIN * SP, wl,            CIN, y, xx, a0, a1, a2, a3);
    conv_accum(st + (size_t)b * CHB,      wl + CIN * 27, HID, y, xx, a0, a1, a2, a3);

    float* o = gate_ptr(out, ws, i) + (size_t)(b * HID + oc) * SP + y * 32 + xx;
    o[0] = a0; o[S2] = a1; o[2*S2] = a2; o[3*S2] = a3;
}

// In-place LayerNorm over the 4096 spatial elems of one (gate,b,c) + activation.
__global__ __launch_bounds__(256) void ln3_act_k(float* __restrict__ out,
                                                 float* __restrict__ ws, int gate0)
{
    const int blk = blockIdx.x;
    const int g = gate0 + (blk >> 9);
    float* p = gate_ptr(out, ws, g) + (size_t)(blk & 511) * SP;
    const int tid = threadIdx.x;

    float s = 0.f, s2 = 0.f;
    for (int k = tid; k < SP; k += 256) { float v = p[k]; s += v; s2 += v * v; }
    #pragma unroll
    for (int off = 32; off > 0; off >>= 1) { s += __shfl_down(s, off); s2 += __shfl_down(s2, off); }
    __shared__ float rs[4], rs2[4], stat[2];
    if ((tid & 63) == 0) { rs[tid >> 6] = s; rs2[tid >> 6] = s2; }
    __syncthreads();
    if (tid == 0) {
        float S  = rs[0] + rs[1] + rs[2] + rs[3];
        float Sq = rs2[0] + rs2[1] + rs2[2] + rs2[3];
        float mu  = S * (1.f / SP);
        float var = Sq * (1.f / SP) - mu * mu;
        stat[0] = mu; stat[1] = rsqrtf(var + EPS);
    }
    __syncthreads();
    const float mu = stat[0], r = stat[1];
    const bool use_tanh = (g == 2 || g == 4);
    for (int k = tid; k < SP; k += 256) {
        float v = (p[k] - mu) * r;
        p[k] = use_tanh ? tanhf(v) : 1.f / (1.f + expf(-v));
    }
}

// scores[b,l] = (1/64) * <r[b], c_history[l,b]> ; partial per block via atomics.
__global__ __launch_bounds__(256) void scores_k(const float* __restrict__ r,
                                                const float* __restrict__ chist,
                                                float* __restrict__ stats)
{
    const int blk = blockIdx.x;          // ((b*5+l)*8 + chunk)
    const int chunk = blk & 7;
    const int bl = blk >> 3;
    const int l = bl % 5;
    const int b = bl / 5;
    const float* rp = r + (size_t)b * CHB;
    const float* cp = chist + (size_t)(l * BATCH + b) * CHB;
    float s = 0.f;
    const int lo = chunk * (CHB / 8);
    for (int k = lo + threadIdx.x; k < lo + CHB / 8; k += 256) s += rp[k] * cp[k];
    #pragma unroll
    for (int off = 32; off > 0; off >>= 1) s += __shfl_down(s, off);
    __shared__ float rsh[4];
    if ((threadIdx.x & 63) == 0) rsh[threadIdx.x >> 6] = s;
    __syncthreads();
    if (threadIdx.x == 0)
        atomicAdd(&stats[l * 8 + b], (rsh[0] + rsh[1] + rsh[2] + rsh[3]) * (1.f / 64.f));
}

// softmax over the batch axis (axis=0 of [B,TAU]) per column l — faithful to source.
__global__ void softmax_k(float* __restrict__ stats)
{
    int l = threadIdx.x;
    if (l < TAU) {
        float mx = -1e30f;
        for (int b = 0; b < BATCH; ++b) mx = fmaxf(mx, stats[l * 8 + b]);
        float e[BATCH]; float sum = 0.f;
        for (int b = 0; b < BATCH; ++b) { e[b] = expf(stats[l * 8 + b] - mx); sum += e[b]; }
        for (int b = 0; b < BATCH; ++b) stats[40 + l * 8 + b] = e[b] / sum;
    }
}

// z = c_history[4,b] + sum_l attn[b,l]*c_history[l,b] ; accumulate LN4 stats per b.
__global__ __launch_bounds__(256) void recall_k(const float* __restrict__ chist,
                                                float* __restrict__ ws)
{
    float* stats = ws + WS_ST_OFF;
    const int blk = blockIdx.x;          // b*1024 + chunk
    const int b = blk >> 10;
    const int idx = (blk & 1023) * 256 + threadIdx.x;   // [0, CHB)
    const float a0 = stats[40 +  0 + b], a1 = stats[40 +  8 + b], a2 = stats[40 + 16 + b];
    const float a3 = stats[40 + 24 + b], a4 = stats[40 + 32 + b];
    const size_t e = (size_t)b * CHB + idx;
    const size_t LB = (size_t)BATCH * CHB;
    float z = chist[4 * LB + e] * (1.f + a4)
            + a0 * chist[0 * LB + e] + a1 * chist[1 * LB + e]
            + a2 * chist[2 * LB + e] + a3 * chist[3 * LB + e];
    ws[WS_Z_OFF + e] = z;

    float s = z, s2 = z * z;
    #pragma unroll
    for (int off = 32; off > 0; off >>= 1) { s += __shfl_down(s, off); s2 += __shfl_down(s2, off); }
    __shared__ float rs[4], rs2[4];
    if ((threadIdx.x & 63) == 0) { rs[threadIdx.x >> 6] = s; rs2[threadIdx.x >> 6] = s2; }
    __syncthreads();
    if (threadIdx.x == 0) {
        atomicAdd(&stats[80 + b], rs[0] + rs[1] + rs[2] + rs[3]);
        atomicAdd(&stats[88 + b], rs2[0] + rs2[1] + rs2[2] + rs2[3]);
    }
}

// c = i*g + LN4(z)*ln_w + ln_b ; m_new = i_p*g_p + f_p*m. Writes d_out slots 4,5.
__global__ __launch_bounds__(256) void cm_k(float* __restrict__ out, float* __restrict__ ws,
                                            const float* __restrict__ m,
                                            const float* __restrict__ lnw,
                                            const float* __restrict__ lnb)
{
    const float* stats = ws + WS_ST_OFF;
    const int blk = blockIdx.x;
    const int b = blk >> 10;
    const int idx = (blk & 1023) * 256 + threadIdx.x;
    const size_t e = (size_t)b * CHB + idx;
    const float mu   = stats[80 + b] * (1.f / CHB);
    const float var  = stats[88 + b] * (1.f / CHB) - mu * mu;
    const float rstd = rsqrtf(var + EPS);
    const float z  = ws[WS_Z_OFF + e];
    const float gi = gate_ptr(out, ws, 1)[e];
    const float gg = gate_ptr(out, ws, 2)[e];
    const float ip = gate_ptr(out, ws, 3)[e];
    const float gp = gate_ptr(out, ws, 4)[e];
    const float fp = gate_ptr(out, ws, 5)[e];
    const float c  = gi * gg + (z - mu) * rstd * lnw[idx] + lnb[idx];
    const float mn = ip * gp + fp * m[e];
    out[(size_t)4 * GATE_SZ + e] = c;    // c_history_new[-1]
    out[(size_t)5 * GATE_SZ + e] = mn;   // m_new
}

// u6 += conv3d(c, Wh[7]) + conv3d(m_new, Wh[8]) + biases
__global__ __launch_bounds__(1024) void conv_o_k(const float* __restrict__ out,
                                                 const float* __restrict__ Wh,
                                                 const float* __restrict__ bh,
                                                 float* __restrict__ ws)
{
    const int blk = blockIdx.x;          // b*64 + oc
    const int b = blk >> 6, oc = blk & 63;
    __shared__ float wl[2 * HID * 27];
    {
        const float* w7 = Wh + (size_t)(7 * HID + oc) * (HID * 27);
        const float* w8 = Wh + (size_t)(8 * HID + oc) * (HID * 27);
        for (int k = threadIdx.x; k < HID * 27; k += 1024) {
            wl[k] = w7[k]; wl[HID * 27 + k] = w8[k];
        }
    }
    __syncthreads();
    const int y  = threadIdx.x >> 5;
    const int xx = threadIdx.x & 31;
    const float bias = bh[7 * HID + oc] + bh[8 * HID + oc];
    float a0 = bias, a1 = bias, a2 = bias, a3 = bias;
    conv_accum(out + (size_t)4 * GATE_SZ + (size_t)b * CHB, wl,            HID, y, xx, a0, a1, a2, a3);
    conv_accum(out + (size_t)5 * GATE_SZ + (size_t)b * CHB, wl + HID * 27, HID, y, xx, a0, a1, a2, a3);
    float* o = ws + (size_t)2 * GATE_SZ + (size_t)(b * HID + oc) * SP + y * 32 + xx;
    o[0] += a0; o[S2] += a1; o[2*S2] += a2; o[3*S2] += a3;
}

// h_new = o * tanh(1x1x1 conv over concat([c, m_new], ch))
__global__ __launch_bounds__(256) void hnew_k(float* __restrict__ out,
                                              const float* __restrict__ ws,
                                              const float* __restrict__ w111,
                                              const float* __restrict__ b111)
{
    const int blk = blockIdx.x;          // (b*64+oc)*16 + chunk
    const int chunk = blk & 15;
    const int bo = blk >> 4;
    const int oc = bo & 63, b = bo >> 6;
    __shared__ float wrow[128];
    if (threadIdx.x < 128) wrow[threadIdx.x] = w111[oc * 128 + threadIdx.x];
    __syncthreads();
    const int s = chunk * 256 + threadIdx.x;
    const float* cp = out + (size_t)4 * GATE_SZ + (size_t)b * CHB + s;
    const float* mp = out + (size_t)5 * GATE_SZ + (size_t)b * CHB + s;
    float acc = b111[oc];
    #pragma unroll 8
    for (int j = 0; j < 64; ++j) acc += wrow[j] * cp[(size_t)j * SP];
    #pragma unroll 8
    for (int j = 0; j < 64; ++j) acc += wrow[64 + j] * mp[(size_t)j * SP];
    const float o = ws[(size_t)2 * GATE_SZ + (size_t)(b * HID + oc) * SP + s];
    out[(size_t)6 * GATE_SZ + (size_t)(b * HID + oc) * SP + s] = o * tanhf(acc);
}

// c_history_new[0:4] = c_history[1:5]
__global__ __launch_bounds__(256) void hist_copy_k(const float* __restrict__ chist,
                                                   float* __restrict__ out)
{
    const size_t i = (size_t)blockIdx.x * 256 + threadIdx.x;   // float4 index, 2097152 total
    const float4* src = (const float4*)(chist + GATE_SZ);
    float4* dst = (float4*)out;
    dst[i] = src[i];
}

extern "C" void kernel_launch(void* const* d_in, const int* in_sizes, int n_in,
                              void* d_out, int out_size, void* d_ws, size_t ws_size,
                              hipStream_t stream)
{
    const float* x    = (const float*)d_in[0];
    const float* ch   = (const float*)d_in[1];
    const float* m    = (const float*)d_in[2];
    const float* h    = (const float*)d_in[3];
    const float* Wx   = (const float*)d_in[4];
    const float* bx   = (const float*)d_in[5];
    const float* Wh   = (const float*)d_in[6];
    const float* bh   = (const float*)d_in[7];
    const float* w111 = (const float*)d_in[8];
    const float* b111 = (const float*)d_in[9];
    const float* lnw  = (const float*)d_in[10];
    const float* lnb  = (const float*)d_in[11];
    float* out = (float*)d_out;
    float* ws  = (float*)d_ws;

    hipMemsetAsync(ws + WS_ST_OFF, 0, 128 * sizeof(float), stream);

    conv_gates_k<<<7 * BATCH * HID, 1024, 0, stream>>>(x, h, m, Wx, bx, Wh, bh, out, ws);
    ln3_act_k<<<6 * BATCH * HID, 256, 0, stream>>>(out, ws, 0);      // gates 0..5
    scores_k<<<BATCH * TAU * 8, 256, 0, stream>>>(out /* r = gate 0 */, ch, ws + WS_ST_OFF);
    softmax_k<<<1, 64, 0, stream>>>(ws + WS_ST_OFF);
    recall_k<<<BATCH * 1024, 256, 0, stream>>>(ch, ws);
    cm_k<<<BATCH * 1024, 256, 0, stream>>>(out, ws, m, lnw, lnb);
    conv_o_k<<<BATCH * HID, 1024, 0, stream>>>(out, Wh, bh, ws);
    ln3_act_k<<<BATCH * HID, 256, 0, stream>>>(out, ws, 6);          // gate 6 (o)
    hnew_k<<<BATCH * HID * 16, 256, 0, stream>>>(out, ws, w111, b111);
    hist_copy_k<<<8192, 256, 0, stream>>>(ch, out);
}

// Round 3
// 658.638 us; speedup vs baseline: 4.2265x; 4.2265x over previous
//
#include <hip/hip_runtime.h>
#include <hip/hip_bf16.h>
#include <math.h>

// Problem constants
#define BATCH 8
#define CIN 16
#define HID 64
#define S2 1024            // 32*32
#define SP 4096            // 4*32*32 spatial elems per channel
#define CHB 262144         // HID*SP per batch
#define TAU 5
#define GATE_SZ 2097152    // BATCH*CHB floats = one gate buffer
#define EPS 1e-5f

// ws layout (floats): [0..3*GATE_SZ) = u4,u5,u6 ; [3G) Z (reused as PCM bf16) ;
// [4G) stats(128 floats). Weight packs live in dead d_out slots (see kernel_launch).
#define WS_Z_OFF   ((size_t)3 * GATE_SZ)
#define WS_ST_OFF  ((size_t)4 * GATE_SZ)

typedef unsigned short u16;
typedef __attribute__((ext_vector_type(8))) short  short8;
typedef __attribute__((ext_vector_type(8))) u16    ushort8;
typedef __attribute__((ext_vector_type(4))) float  f32x4;

#define N7 (7*27*64*96)
#define NO (27*64*128)
#define N1 (64*128)

__device__ __forceinline__ u16 f2b(float v) {
    __hip_bfloat16 h = __float2bfloat16(v);
    u16 r; __builtin_memcpy(&r, &h, 2); return r;
}

__device__ __forceinline__ float* gate_ptr(float* out, float* ws, int g) {
    return (g < 4) ? (out + (size_t)g * GATE_SZ) : (ws + (size_t)(g - 4) * GATE_SZ);
}

// ---- weight pack: A7[g][tap][oc][96], Ao[tap][oc][128], A111[oc][128] (bf16) ----
__global__ __launch_bounds__(256) void pack_w_k(const float* __restrict__ Wx,
                                                const float* __restrict__ Wh,
                                                const float* __restrict__ w111,
                                                u16* __restrict__ A7, u16* __restrict__ Ao,
                                                u16* __restrict__ A111)
{
    const int idx = blockIdx.x * 256 + threadIdx.x;
    if (idx < N7) {
        const int k = idx % 96, oc = (idx / 96) % 64, tap = (idx / (96*64)) % 27, g = idx / (96*64*27);
        float v = 0.f;
        if (k < 16)      v = Wx[((size_t)(g*64 + oc)*16 + k)      * 27 + tap];
        else if (k < 80) v = Wh[((size_t)(g*64 + oc)*64 + (k-16)) * 27 + tap];
        A7[idx] = f2b(v);
    } else if (idx < N7 + NO) {
        const int j = idx - N7;
        const int k = j % 128, oc = (j / 128) % 64, tap = j / (128*64);
        float v = (k < 64) ? Wh[((size_t)(7*64 + oc)*64 + k)      * 27 + tap]
                           : Wh[((size_t)(8*64 + oc)*64 + (k-64)) * 27 + tap];
        Ao[j] = f2b(v);
    } else if (idx < N7 + NO + N1) {
        const int j = idx - N7 - NO;
        A111[j] = f2b(w111[j]);
    }
}

// ---- input pack: XH[b][4096][96], XM[b][4096][96] (bf16, ch-minor) ----
__global__ __launch_bounds__(256) void pack_xhm_k(const float* __restrict__ x,
                                                  const float* __restrict__ h,
                                                  const float* __restrict__ m,
                                                  u16* __restrict__ XH, u16* __restrict__ XM)
{
    __shared__ float t[144][65];
    const int bi = blockIdx.x, b = bi >> 6, s0 = (bi & 63) << 6;
    for (int i = threadIdx.x; i < 144*64; i += 256) {
        const int row = i >> 6, sc = i & 63;
        float v;
        if (row < 16)      v = x[((size_t)b*16 + row)      * SP + s0 + sc];
        else if (row < 80) v = h[((size_t)b*64 + (row-16)) * SP + s0 + sc];
        else               v = m[((size_t)b*64 + (row-80)) * SP + s0 + sc];
        t[row][sc] = v;
    }
    __syncthreads();
    for (int j = threadIdx.x; j < 64*96; j += 256) {
        const int s = j / 96, ch = j % 96;
        const size_t o = ((size_t)b*4096 + s0 + s) * 96 + ch;
        XH[o] = f2b(ch < 80 ? t[ch][s] : 0.f);
        XM[o] = f2b(ch < 16 ? t[ch][s] : (ch < 80 ? t[ch + 64][s] : 0.f));
    }
}

// ---- pack c,m_new -> PCM[b][4096][128] bf16 ----
__global__ __launch_bounds__(256) void pack_pcm_k(const float* __restrict__ c,
                                                  const float* __restrict__ mn,
                                                  u16* __restrict__ PCM)
{
    __shared__ float t[128][65];
    const int bi = blockIdx.x, b = bi >> 6, s0 = (bi & 63) << 6;
    for (int i = threadIdx.x; i < 128*64; i += 256) {
        const int row = i >> 6, sc = i & 63;
        float v = (row < 64) ? c [((size_t)b*64 + row)      * SP + s0 + sc]
                             : mn[((size_t)b*64 + (row-64)) * SP + s0 + sc];
        t[row][sc] = v;
    }
    __syncthreads();
    for (int j = threadIdx.x; j < 64*128; j += 256) {
        const int s = j >> 7, ch = j & 127;
        PCM[((size_t)b*4096 + s0 + s) * 128 + ch] = f2b(t[ch][s]);
    }
}

// ---- implicit-GEMM conv via MFMA 16x16x32 bf16 ----
// MODE 0: 7 gate convs (K=96, 27 taps, X = XH or XM per gate, bias bx+bh, write)
// MODE 1: o-gate state conv (K=128, 27 taps, X=PCM, bias bh[7]+bh[8], accumulate into ws u6)
// MODE 2: 1x1x1 conv (K=128, 1 tap, X=PCM, bias b111, write v into ws slot 0)
template<int KCH, int TAPS, int NR, int MODE>
__global__ __launch_bounds__(256) void conv_mfma_k(
    const u16* __restrict__ XA, const u16* __restrict__ XB,
    const u16* __restrict__ Apack,
    const float* __restrict__ bxp, const float* __restrict__ bhp,
    const float* __restrict__ b111,
    float* __restrict__ out, float* __restrict__ ws)
{
    constexpr int YT   = NR + 2;        // y rows in tile (with halo)
    constexpr int ROWS = 4 * YT * 34;   // t * y * x(with halo)
    constexpr int PADK = 40;            // 32 ch + pad (80B rows: 16B-aligned, 2-way banks)
    __shared__ __align__(16) u16 xs[ROWS * PADK];

    const int bi = blockIdx.x;
    int g = 0, b, y0;
    const u16* X; const u16* Ag; float* outp;
    if (MODE == 0) {
        constexpr int YB = 32 / NR;
        g  = bi / (8 * YB);
        b  = (bi / YB) % 8;
        y0 = (bi % YB) * NR;
        X  = (g >= 3 && g <= 5) ? XB : XA;
        Ag = Apack + (size_t)g * TAPS * 64 * KCH;
        outp = gate_ptr(out, ws, g) + (size_t)b * CHB;
    } else {
        b = bi >> 5; y0 = bi & 31;
        X = XA; Ag = Apack;
        outp = ((MODE == 1) ? (ws + (size_t)2 * GATE_SZ) : ws) + (size_t)b * CHB;
    }
    const u16* Xb = X + (size_t)b * 4096 * KCH;

    const int tid  = threadIdx.x;
    const int w    = tid >> 6;          // wave = output t-plane
    const int lane = tid & 63;
    const int xn   = lane & 15, quad = lane >> 4;

    f32x4 acc[4][2 * NR] = {};

    for (int kc = 0; kc < KCH / 32; ++kc) {
        if (kc) __syncthreads();
        // stage 32-channel slab of the (t, y-halo, x-halo) tile into LDS
        for (int cix = tid; cix < ROWS * 4; cix += 256) {
            const int r = cix >> 2, sub = cix & 3;
            const int t = r / (YT * 34), rem = r % (YT * 34);
            const int yy = rem / 34, xx = rem % 34;
            const int gy = y0 + yy - 1, gx = xx - 1;
            ushort8 v = {0, 0, 0, 0, 0, 0, 0, 0};
            if ((unsigned)gy < 32u && (unsigned)gx < 32u)
                v = *(const ushort8*)&Xb[(size_t)(t * 1024 + gy * 32 + gx) * KCH + kc * 32 + sub * 8];
            *(ushort8*)&xs[r * PADK + sub * 8] = v;
        }
        __syncthreads();

        for (int tap = 0; tap < TAPS; ++tap) {
            int kd, ky, kx;
            if (TAPS == 27) { kd = tap / 9; ky = (tap / 3) % 3; kx = tap % 3; }
            else            { kd = 1; ky = 1; kx = 1; }
            const int tin = w + kd - 1;
            if (TAPS == 27 && (unsigned)tin >= 4u) continue;   // wave-uniform
            short8 a[4];
            #pragma unroll
            for (int mt = 0; mt < 4; ++mt)
                a[mt] = *(const short8*)&Ag[(size_t)(tap * 64 + mt * 16 + xn) * KCH + kc * 32 + quad * 8];
            #pragma unroll
            for (int nt = 0; nt < 2 * NR; ++nt) {
                const int ysub = nt >> 1, xh = nt & 1;
                const short8 bf = *(const short8*)
                    &xs[((tin * YT + ysub + ky) * 34 + xh * 16 + xn + kx) * PADK + quad * 8];
                #pragma unroll
                for (int mt = 0; mt < 4; ++mt)
                    acc[mt][nt] = __builtin_amdgcn_mfma_f32_16x16x32_bf16(a[mt], bf, acc[mt][nt], 0, 0, 0);
            }
        }
    }

    // epilogue: C/D layout col=lane&15, row=quad*4+reg
    #pragma unroll
    for (int mt = 0; mt < 4; ++mt)
    #pragma unroll
    for (int nt = 0; nt < 2 * NR; ++nt) {
        const int ysub = nt >> 1, xh = nt & 1;
        const int sp = w * 1024 + (y0 + ysub) * 32 + xh * 16 + xn;
        #pragma unroll
        for (int reg = 0; reg < 4; ++reg) {
            const int oc = mt * 16 + quad * 4 + reg;
            float bias;
            if (MODE == 0)      bias = bxp[g * 64 + oc] + bhp[g * 64 + oc];
            else if (MODE == 1) bias = bhp[7 * 64 + oc] + bhp[8 * 64 + oc];
            else                bias = b111[oc];
            const float vv = acc[mt][nt][reg] + bias;
            float* p = outp + (size_t)oc * SP + sp;
            if (MODE == 1) *p += vv; else *p = vv;
        }
    }
}

// ---- LayerNorm over 4096 spatial elems of one (gate,b,c), in place, + activation ----
__global__ __launch_bounds__(256) void ln3_act_k(float* __restrict__ out,
                                                 float* __restrict__ ws, int gate0)
{
    const int blk = blockIdx.x;
    const int g = gate0 + (blk >> 9);
    float* p = gate_ptr(out, ws, g) + (size_t)(blk & 511) * SP;
    const int tid = threadIdx.x;

    float s = 0.f, s2 = 0.f;
    for (int k = tid; k < SP; k += 256) { float v = p[k]; s += v; s2 += v * v; }
    #pragma unroll
    for (int off = 32; off > 0; off >>= 1) { s += __shfl_down(s, off); s2 += __shfl_down(s2, off); }
    __shared__ float rs[4], rs2[4], stat[2];
    if ((tid & 63) == 0) { rs[tid >> 6] = s; rs2[tid >> 6] = s2; }
    __syncthreads();
    if (tid == 0) {
        float S  = rs[0] + rs[1] + rs[2] + rs[3];
        float Sq = rs2[0] + rs2[1] + rs2[2] + rs2[3];
        float mu  = S * (1.f / SP);
        float var = Sq * (1.f / SP) - mu * mu;
        stat[0] = mu; stat[1] = rsqrtf(var + EPS);
    }
    __syncthreads();
    const float mu = stat[0], r = stat[1];
    const bool use_tanh = (g == 2 || g == 4);
    for (int k = tid; k < SP; k += 256) {
        float v = (p[k] - mu) * r;
        p[k] = use_tanh ? tanhf(v) : 1.f / (1.f + expf(-v));
    }
}

// ---- attention scores / softmax(dim=0) / recall+LN4 stats / c,m update ----
__global__ __launch_bounds__(256) void scores_k(const float* __restrict__ r,
                                                const float* __restrict__ chist,
                                                float* __restrict__ stats)
{
    const int blk = blockIdx.x;
    const int chunk = blk & 7;
    const int bl = blk >> 3;
    const int l = bl % 5, b = bl / 5;
    const float* rp = r + (size_t)b * CHB;
    const float* cp = chist + (size_t)(l * BATCH + b) * CHB;
    float s = 0.f;
    const int lo = chunk * (CHB / 8);
    for (int k = lo + threadIdx.x; k < lo + CHB / 8; k += 256) s += rp[k] * cp[k];
    #pragma unroll
    for (int off = 32; off > 0; off >>= 1) s += __shfl_down(s, off);
    __shared__ float rsh[4];
    if ((threadIdx.x & 63) == 0) rsh[threadIdx.x >> 6] = s;
    __syncthreads();
    if (threadIdx.x == 0)
        atomicAdd(&stats[l * 8 + b], (rsh[0] + rsh[1] + rsh[2] + rsh[3]) * (1.f / 64.f));
}

__global__ void softmax_k(float* __restrict__ stats)
{
    int l = threadIdx.x;
    if (l < TAU) {
        float mx = -1e30f;
        for (int b = 0; b < BATCH; ++b) mx = fmaxf(mx, stats[l * 8 + b]);
        float e[BATCH]; float sum = 0.f;
        for (int b = 0; b < BATCH; ++b) { e[b] = expf(stats[l * 8 + b] - mx); sum += e[b]; }
        for (int b = 0; b < BATCH; ++b) stats[40 + l * 8 + b] = e[b] / sum;
    }
}

__global__ __launch_bounds__(256) void recall_k(const float* __restrict__ chist,
                                                float* __restrict__ ws)
{
    float* stats = ws + WS_ST_OFF;
    const int blk = blockIdx.x;
    const int b = blk >> 10;
    const int idx = (blk & 1023) * 256 + threadIdx.x;
    const float a0 = stats[40 +  0 + b], a1 = stats[40 +  8 + b], a2 = stats[40 + 16 + b];
    const float a3 = stats[40 + 24 + b], a4 = stats[40 + 32 + b];
    const size_t e = (size_t)b * CHB + idx;
    const size_t LB = (size_t)BATCH * CHB;
    float z = chist[4 * LB + e] * (1.f + a4)
            + a0 * chist[0 * LB + e] + a1 * chist[1 * LB + e]
            + a2 * chist[2 * LB + e] + a3 * chist[3 * LB + e];
    ws[WS_Z_OFF + e] = z;

    float s = z, s2 = z * z;
    #pragma unroll
    for (int off = 32; off > 0; off >>= 1) { s += __shfl_down(s, off); s2 += __shfl_down(s2, off); }
    __shared__ float rs[4], rs2[4];
    if ((threadIdx.x & 63) == 0) { rs[threadIdx.x >> 6] = s; rs2[threadIdx.x >> 6] = s2; }
    __syncthreads();
    if (threadIdx.x == 0) {
        atomicAdd(&stats[80 + b], rs[0] + rs[1] + rs[2] + rs[3]);
        atomicAdd(&stats[88 + b], rs2[0] + rs2[1] + rs2[2] + rs2[3]);
    }
}

__global__ __launch_bounds__(256) void cm_k(float* __restrict__ out, float* __restrict__ ws,
                                            const float* __restrict__ m,
                                            const float* __restrict__ lnw,
                                            const float* __restrict__ lnb)
{
    const float* stats = ws + WS_ST_OFF;
    const int blk = blockIdx.x;
    const int b = blk >> 10;
    const int idx = (blk & 1023) * 256 + threadIdx.x;
    const size_t e = (size_t)b * CHB + idx;
    const float mu   = stats[80 + b] * (1.f / CHB);
    const float var  = stats[88 + b] * (1.f / CHB) - mu * mu;
    const float rstd = rsqrtf(var + EPS);
    const float z  = ws[WS_Z_OFF + e];
    const float gi = gate_ptr(out, ws, 1)[e];
    const float gg = gate_ptr(out, ws, 2)[e];
    const float ip = gate_ptr(out, ws, 3)[e];
    const float gp = gate_ptr(out, ws, 4)[e];
    const float fp = gate_ptr(out, ws, 5)[e];
    const float c  = gi * gg + (z - mu) * rstd * lnw[idx] + lnb[idx];
    const float mn = ip * gp + fp * m[e];
    out[(size_t)4 * GATE_SZ + e] = c;
    out[(size_t)5 * GATE_SZ + e] = mn;
}

// ---- h_new = o * tanh(v) ----
__global__ __launch_bounds__(256) void hnew_elem_k(const float* __restrict__ o,
                                                   const float* __restrict__ v,
                                                   float* __restrict__ hn)
{
    const size_t i = (size_t)blockIdx.x * 256 + threadIdx.x;   // float4 idx, GATE_SZ/4 total
    float4 ov = ((const float4*)o)[i], vv = ((const float4*)v)[i];
    float4 r;
    r.x = ov.x * tanhf(vv.x); r.y = ov.y * tanhf(vv.y);
    r.z = ov.z * tanhf(vv.z); r.w = ov.w * tanhf(vv.w);
    ((float4*)hn)[i] = r;
}

// ---- c_history_new[0:4] = c_history[1:5] ----
__global__ __launch_bounds__(256) void hist_copy_k(const float* __restrict__ chist,
                                                   float* __restrict__ out)
{
    const size_t i = (size_t)blockIdx.x * 256 + threadIdx.x;
    const float4* src = (const float4*)(chist + GATE_SZ);
    float4* dst = (float4*)out;
    dst[i] = src[i];
}

extern "C" void kernel_launch(void* const* d_in, const int* in_sizes, int n_in,
                              void* d_out, int out_size, void* d_ws, size_t ws_size,
                              hipStream_t stream)
{
    const float* x    = (const float*)d_in[0];
    const float* ch   = (const float*)d_in[1];
    const float* m    = (const float*)d_in[2];
    const float* h    = (const float*)d_in[3];
    const float* Wx   = (const float*)d_in[4];
    const float* bx   = (const float*)d_in[5];
    const float* Wh   = (const float*)d_in[6];
    const float* bh   = (const float*)d_in[7];
    const float* w111 = (const float*)d_in[8];
    const float* b111 = (const float*)d_in[9];
    const float* lnw  = (const float*)d_in[10];
    const float* lnb  = (const float*)d_in[11];
    float* out = (float*)d_out;
    float* ws  = (float*)d_ws;

    // Scratch placement in DEAD d_out slots (ws stays within the proven
    // 4*GATE_SZ+128-float footprint):
    //   slot 4: XH (6 MB)  — dead until cm_k writes c
    //   slot 5: A7 (2.2 MB) — dead until cm_k writes m_new; A7 only used before cm_k
    //   slot 6: XM (6 MB) + Ao/A111 (0.46 MB) — dead until hnew writes h_new
    u16* XH   = (u16*)(out + (size_t)4 * GATE_SZ);
    u16* A7   = (u16*)(out + (size_t)5 * GATE_SZ);
    u16* XM   = (u16*)(out + (size_t)6 * GATE_SZ);
    u16* Ao   = XM + (size_t)BATCH * 4096 * 96;      // behind XM, same slot
    u16* A111 = Ao + (size_t)NO;
    u16* PCM  = (u16*)(ws + WS_Z_OFF);               // reuses Z region after cm_k
    float* stats = ws + WS_ST_OFF;

    hipMemsetAsync(stats, 0, 128 * sizeof(float), stream);
    pack_w_k<<<(N7 + NO + N1 + 255) / 256, 256, 0, stream>>>(Wx, Wh, w111, A7, Ao, A111);
    pack_xhm_k<<<512, 256, 0, stream>>>(x, h, m, XH, XM);

    conv_mfma_k<96, 27, 2, 0><<<896, 256, 0, stream>>>(XH, XM, A7, bx, bh, nullptr, out, ws);
    ln3_act_k<<<3072, 256, 0, stream>>>(out, ws, 0);                 // gates 0..5

    scores_k<<<BATCH * TAU * 8, 256, 0, stream>>>(out, ch, stats);   // r = gate 0
    softmax_k<<<1, 64, 0, stream>>>(stats);
    recall_k<<<8192, 256, 0, stream>>>(ch, ws);
    cm_k<<<8192, 256, 0, stream>>>(out, ws, m, lnw, lnb);

    pack_pcm_k<<<512, 256, 0, stream>>>(out + (size_t)4 * GATE_SZ, out + (size_t)5 * GATE_SZ, PCM);
    conv_mfma_k<128, 27, 1, 1><<<256, 256, 0, stream>>>(PCM, nullptr, Ao, nullptr, bh, nullptr, out, ws);
    ln3_act_k<<<512, 256, 0, stream>>>(out, ws, 6);                  // gate 6 (o)
    conv_mfma_k<128, 1, 1, 2><<<256, 256, 0, stream>>>(PCM, nullptr, A111, nullptr, nullptr, b111, out, ws);

    hnew_elem_k<<<GATE_SZ / 1024, 256, 0, stream>>>(ws + (size_t)2 * GATE_SZ, ws, out + (size_t)6 * GATE_SZ);
    hist_copy_k<<<8192, 256, 0, stream>>>(ch, out);
}

// Round 4
// 458.888 us; speedup vs baseline: 6.0663x; 1.4353x over previous
//
#include <hip/hip_runtime.h>
#include <hip/hip_bf16.h>
#include <math.h>

// Problem constants
#define BATCH 8
#define CIN 16
#define HID 64
#define S2 1024            // 32*32
#define SP 4096            // 4*32*32 spatial elems per channel
#define CHB 262144         // HID*SP per batch
#define TAU 5
#define GATE_SZ 2097152    // BATCH*CHB floats = one gate buffer
#define EPS 1e-5f

// ws layout (floats): [0..3*GATE_SZ) = u4,u5,u6 ; [3G) Z (reused as PCM bf16) ;
// [4G) stats(128 floats). Weight packs live in dead d_out slots (see kernel_launch).
#define WS_Z_OFF   ((size_t)3 * GATE_SZ)
#define WS_ST_OFF  ((size_t)4 * GATE_SZ)
// stats: scores[0..39] (l*8+b), attn[40..79], ln4 mu[80..87], ln4 rstd[88..95]

typedef unsigned short u16;
typedef __attribute__((ext_vector_type(8))) short  short8;
typedef __attribute__((ext_vector_type(8))) u16    ushort8;
typedef __attribute__((ext_vector_type(4))) float  f32x4;

#define N7 (7*27*64*96)
#define NO (27*64*128)
#define N1 (64*128)

__device__ __forceinline__ u16 f2b(float v) {
    __hip_bfloat16 h = __float2bfloat16(v);
    u16 r; __builtin_memcpy(&r, &h, 2); return r;
}

__device__ __forceinline__ float* gate_ptr(float* out, float* ws, int g) {
    return (g < 4) ? (out + (size_t)g * GATE_SZ) : (ws + (size_t)(g - 4) * GATE_SZ);
}

// ---- weight pack: A7[g][tap][oc][96], Ao[tap][oc][128], A111[oc][128] (bf16) ----
__global__ __launch_bounds__(256) void pack_w_k(const float* __restrict__ Wx,
                                                const float* __restrict__ Wh,
                                                const float* __restrict__ w111,
                                                u16* __restrict__ A7, u16* __restrict__ Ao,
                                                u16* __restrict__ A111)
{
    const int idx = blockIdx.x * 256 + threadIdx.x;
    if (idx < N7) {
        const int k = idx % 96, oc = (idx / 96) % 64, tap = (idx / (96*64)) % 27, g = idx / (96*64*27);
        float v = 0.f;
        if (k < 16)      v = Wx[((size_t)(g*64 + oc)*16 + k)      * 27 + tap];
        else if (k < 80) v = Wh[((size_t)(g*64 + oc)*64 + (k-16)) * 27 + tap];
        A7[idx] = f2b(v);
    } else if (idx < N7 + NO) {
        const int j = idx - N7;
        const int k = j % 128, oc = (j / 128) % 64, tap = j / (128*64);
        float v = (k < 64) ? Wh[((size_t)(7*64 + oc)*64 + k)      * 27 + tap]
                           : Wh[((size_t)(8*64 + oc)*64 + (k-64)) * 27 + tap];
        Ao[j] = f2b(v);
    } else if (idx < N7 + NO + N1) {
        const int j = idx - N7 - NO;
        A111[j] = f2b(w111[j]);
    }
}

// ---- input pack: XH[b][4096][96], XM[b][4096][96] (bf16, ch-minor) ----
__global__ __launch_bounds__(256) void pack_xhm_k(const float* __restrict__ x,
                                                  const float* __restrict__ h,
                                                  const float* __restrict__ m,
                                                  u16* __restrict__ XH, u16* __restrict__ XM)
{
    __shared__ float t[144][65];
    const int bi = blockIdx.x, b = bi >> 6, s0 = (bi & 63) << 6;
    for (int i = threadIdx.x; i < 144*64; i += 256) {
        const int row = i >> 6, sc = i & 63;
        float v;
        if (row < 16)      v = x[((size_t)b*16 + row)      * SP + s0 + sc];
        else if (row < 80) v = h[((size_t)b*64 + (row-16)) * SP + s0 + sc];
        else               v = m[((size_t)b*64 + (row-80)) * SP + s0 + sc];
        t[row][sc] = v;
    }
    __syncthreads();
    for (int j = threadIdx.x; j < 64*96; j += 256) {
        const int s = j / 96, ch = j % 96;
        const size_t o = ((size_t)b*4096 + s0 + s) * 96 + ch;
        XH[o] = f2b(ch < 80 ? t[ch][s] : 0.f);
        XM[o] = f2b(ch < 16 ? t[ch][s] : (ch < 80 ? t[ch + 64][s] : 0.f));
    }
}

// ---- pack c,m_new -> PCM[b][4096][128] bf16 ----
__global__ __launch_bounds__(256) void pack_pcm_k(const float* __restrict__ c,
                                                  const float* __restrict__ mn,
                                                  u16* __restrict__ PCM)
{
    __shared__ float t[128][65];
    const int bi = blockIdx.x, b = bi >> 6, s0 = (bi & 63) << 6;
    for (int i = threadIdx.x; i < 128*64; i += 256) {
        const int row = i >> 6, sc = i & 63;
        float v = (row < 64) ? c [((size_t)b*64 + row)      * SP + s0 + sc]
                             : mn[((size_t)b*64 + (row-64)) * SP + s0 + sc];
        t[row][sc] = v;
    }
    __syncthreads();
    for (int j = threadIdx.x; j < 64*128; j += 256) {
        const int s = j >> 7, ch = j & 127;
        PCM[((size_t)b*4096 + s0 + s) * 128 + ch] = f2b(t[ch][s]);
    }
}

// ---- implicit-GEMM conv via MFMA 16x16x32 bf16 ----
// MODE 0: 7 gate convs (K=96, 27 taps, X = XH or XM per gate, bias bx+bh, write)
// MODE 1: o-gate state conv (K=128, 27 taps, X=PCM, bias bh[7]+bh[8], accumulate into ws u6)
// MODE 2: 1x1x1 conv (K=128, 1 tap, X=PCM, bias b111, write v into ws slot 0)
template<int KCH, int TAPS, int NR, int MODE>
__global__ __launch_bounds__(256) void conv_mfma_k(
    const u16* __restrict__ XA, const u16* __restrict__ XB,
    const u16* __restrict__ Apack,
    const float* __restrict__ bxp, const float* __restrict__ bhp,
    const float* __restrict__ b111,
    float* __restrict__ out, float* __restrict__ ws)
{
    constexpr int YT   = NR + 2;        // y rows in tile (with halo)
    constexpr int ROWS = 4 * YT * 34;   // t * y * x(with halo)
    constexpr int PADK = 40;            // 32 ch + pad (80B rows: 16B-aligned, 2-way banks)
    __shared__ __align__(16) u16 xs[ROWS * PADK];

    const int bi = blockIdx.x;
    int g = 0, b, y0;
    const u16* X; const u16* Ag; float* outp;
    if (MODE == 0) {
        constexpr int YB = 32 / NR;
        g  = bi / (8 * YB);
        b  = (bi / YB) % 8;
        y0 = (bi % YB) * NR;
        X  = (g >= 3 && g <= 5) ? XB : XA;
        Ag = Apack + (size_t)g * TAPS * 64 * KCH;
        outp = gate_ptr(out, ws, g) + (size_t)b * CHB;
    } else {
        b = bi >> 5; y0 = bi & 31;
        X = XA; Ag = Apack;
        outp = ((MODE == 1) ? (ws + (size_t)2 * GATE_SZ) : ws) + (size_t)b * CHB;
    }
    const u16* Xb = X + (size_t)b * 4096 * KCH;

    const int tid  = threadIdx.x;
    const int w    = tid >> 6;          // wave = output t-plane
    const int lane = tid & 63;
    const int xn   = lane & 15, quad = lane >> 4;

    f32x4 acc[4][2 * NR] = {};

    for (int kc = 0; kc < KCH / 32; ++kc) {
        if (kc) __syncthreads();
        // stage 32-channel slab of the (t, y-halo, x-halo) tile into LDS
        for (int cix = tid; cix < ROWS * 4; cix += 256) {
            const int r = cix >> 2, sub = cix & 3;
            const int t = r / (YT * 34), rem = r % (YT * 34);
            const int yy = rem / 34, xx = rem % 34;
            const int gy = y0 + yy - 1, gx = xx - 1;
            ushort8 v = {0, 0, 0, 0, 0, 0, 0, 0};
            if ((unsigned)gy < 32u && (unsigned)gx < 32u)
                v = *(const ushort8*)&Xb[(size_t)(t * 1024 + gy * 32 + gx) * KCH + kc * 32 + sub * 8];
            *(ushort8*)&xs[r * PADK + sub * 8] = v;
        }
        __syncthreads();

        for (int tap = 0; tap < TAPS; ++tap) {
            int kd, ky, kx;
            if (TAPS == 27) { kd = tap / 9; ky = (tap / 3) % 3; kx = tap % 3; }
            else            { kd = 1; ky = 1; kx = 1; }
            const int tin = w + kd - 1;
            if (TAPS == 27 && (unsigned)tin >= 4u) continue;   // wave-uniform
            short8 a[4];
            #pragma unroll
            for (int mt = 0; mt < 4; ++mt)
                a[mt] = *(const short8*)&Ag[(size_t)(tap * 64 + mt * 16 + xn) * KCH + kc * 32 + quad * 8];
            #pragma unroll
            for (int nt = 0; nt < 2 * NR; ++nt) {
                const int ysub = nt >> 1, xh = nt & 1;
                const short8 bf = *(const short8*)
                    &xs[((tin * YT + ysub + ky) * 34 + xh * 16 + xn + kx) * PADK + quad * 8];
                #pragma unroll
                for (int mt = 0; mt < 4; ++mt)
                    acc[mt][nt] = __builtin_amdgcn_mfma_f32_16x16x32_bf16(a[mt], bf, acc[mt][nt], 0, 0, 0);
            }
        }
    }

    // epilogue: C/D layout col=lane&15, row=quad*4+reg
    #pragma unroll
    for (int mt = 0; mt < 4; ++mt)
    #pragma unroll
    for (int nt = 0; nt < 2 * NR; ++nt) {
        const int ysub = nt >> 1, xh = nt & 1;
        const int sp = w * 1024 + (y0 + ysub) * 32 + xh * 16 + xn;
        #pragma unroll
        for (int reg = 0; reg < 4; ++reg) {
            const int oc = mt * 16 + quad * 4 + reg;
            float bias;
            if (MODE == 0)      bias = bxp[g * 64 + oc] + bhp[g * 64 + oc];
            else if (MODE == 1) bias = bhp[7 * 64 + oc] + bhp[8 * 64 + oc];
            else                bias = b111[oc];
            const float vv = acc[mt][nt][reg] + bias;
            float* p = outp + (size_t)oc * SP + sp;
            if (MODE == 1) *p += vv; else *p = vv;
        }
    }
}

// ---- LayerNorm over 4096 spatial elems of one (gate,b,c), in place, + activation ----
__global__ __launch_bounds__(256) void ln3_act_k(float* __restrict__ out,
                                                 float* __restrict__ ws, int gate0)
{
    const int blk = blockIdx.x;
    const int g = gate0 + (blk >> 9);
    float* p = gate_ptr(out, ws, g) + (size_t)(blk & 511) * SP;
    const int tid = threadIdx.x;

    float s = 0.f, s2 = 0.f;
    for (int k = tid; k < SP; k += 256) { float v = p[k]; s += v; s2 += v * v; }
    #pragma unroll
    for (int off = 32; off > 0; off >>= 1) { s += __shfl_down(s, off); s2 += __shfl_down(s2, off); }
    __shared__ float rs[4], rs2[4], stat[2];
    if ((tid & 63) == 0) { rs[tid >> 6] = s; rs2[tid >> 6] = s2; }
    __syncthreads();
    if (tid == 0) {
        float S  = rs[0] + rs[1] + rs[2] + rs[3];
        float Sq = rs2[0] + rs2[1] + rs2[2] + rs2[3];
        float mu  = S * (1.f / SP);
        float var = Sq * (1.f / SP) - mu * mu;
        stat[0] = mu; stat[1] = rsqrtf(var + EPS);
    }
    __syncthreads();
    const float mu = stat[0], r = stat[1];
    const bool use_tanh = (g == 2 || g == 4);
    for (int k = tid; k < SP; k += 256) {
        float v = (p[k] - mu) * r;
        p[k] = use_tanh ? tanhf(v) : 1.f / (1.f + expf(-v));
    }
}

// ---- attention scores / softmax(dim=0) ----
__global__ __launch_bounds__(256) void scores_k(const float* __restrict__ r,
                                                const float* __restrict__ chist,
                                                float* __restrict__ stats)
{
    const int blk = blockIdx.x;
    const int chunk = blk & 7;
    const int bl = blk >> 3;
    const int l = bl % 5, b = bl / 5;
    const float* rp = r + (size_t)b * CHB;
    const float* cp = chist + (size_t)(l * BATCH + b) * CHB;
    float s = 0.f;
    const int lo = chunk * (CHB / 8);
    for (int k = lo + threadIdx.x; k < lo + CHB / 8; k += 256) s += rp[k] * cp[k];
    #pragma unroll
    for (int off = 32; off > 0; off >>= 1) s += __shfl_down(s, off);
    __shared__ float rsh[4];
    if ((threadIdx.x & 63) == 0) rsh[threadIdx.x >> 6] = s;
    __syncthreads();
    if (threadIdx.x == 0)
        atomicAdd(&stats[l * 8 + b], (rsh[0] + rsh[1] + rsh[2] + rsh[3]) * (1.f / 64.f));
}

__global__ void softmax_k(float* __restrict__ stats)
{
    int l = threadIdx.x;
    if (l < TAU) {
        float mx = -1e30f;
        for (int b = 0; b < BATCH; ++b) mx = fmaxf(mx, stats[l * 8 + b]);
        float e[BATCH]; float sum = 0.f;
        for (int b = 0; b < BATCH; ++b) { e[b] = expf(stats[l * 8 + b] - mx); sum += e[b]; }
        for (int b = 0; b < BATCH; ++b) stats[40 + l * 8 + b] = e[b] / sum;
    }
}

// ---- z = chist[4,b] + sum_l attn[b,l]*chist[l,b]; per-block partials (NO atomics) ----
__global__ __launch_bounds__(256) void recall_k(const float* __restrict__ chist,
                                                float* __restrict__ ws,
                                                float* __restrict__ part)
{
    const float* stats = ws + WS_ST_OFF;
    const int blk = blockIdx.x;
    const int b = blk >> 10;
    const int idx = (blk & 1023) * 256 + threadIdx.x;
    const float a0 = stats[40 +  0 + b], a1 = stats[40 +  8 + b], a2 = stats[40 + 16 + b];
    const float a3 = stats[40 + 24 + b], a4 = stats[40 + 32 + b];
    const size_t e = (size_t)b * CHB + idx;
    const size_t LB = (size_t)BATCH * CHB;
    float z = chist[4 * LB + e] * (1.f + a4)
            + a0 * chist[0 * LB + e] + a1 * chist[1 * LB + e]
            + a2 * chist[2 * LB + e] + a3 * chist[3 * LB + e];
    ws[WS_Z_OFF + e] = z;

    float s = z, s2 = z * z;
    #pragma unroll
    for (int off = 32; off > 0; off >>= 1) { s += __shfl_down(s, off); s2 += __shfl_down(s2, off); }
    __shared__ float rs[4], rs2[4];
    if ((threadIdx.x & 63) == 0) { rs[threadIdx.x >> 6] = s; rs2[threadIdx.x >> 6] = s2; }
    __syncthreads();
    if (threadIdx.x == 0) {
        part[blk]        = rs[0] + rs[1] + rs[2] + rs[3];
        part[8192 + blk] = rs2[0] + rs2[1] + rs2[2] + rs2[3];
    }
}

// ---- reduce 1024 partials per batch -> stats[80+b]=mu, stats[88+b]=rstd ----
__global__ __launch_bounds__(256) void ln4_stats_k(const float* __restrict__ part,
                                                   float* __restrict__ stats)
{
    const int b = blockIdx.x;
    float s = 0.f, s2 = 0.f;
    for (int j = threadIdx.x; j < 1024; j += 256) {
        s  += part[b * 1024 + j];
        s2 += part[8192 + b * 1024 + j];
    }
    #pragma unroll
    for (int off = 32; off > 0; off >>= 1) { s += __shfl_down(s, off); s2 += __shfl_down(s2, off); }
    __shared__ float rs[4], rs2[4];
    if ((threadIdx.x & 63) == 0) { rs[threadIdx.x >> 6] = s; rs2[threadIdx.x >> 6] = s2; }
    __syncthreads();
    if (threadIdx.x == 0) {
        float S  = rs[0] + rs[1] + rs[2] + rs[3];
        float Sq = rs2[0] + rs2[1] + rs2[2] + rs2[3];
        float mu  = S * (1.f / CHB);
        float var = Sq * (1.f / CHB) - mu * mu;
        stats[80 + b] = mu;
        stats[88 + b] = rsqrtf(var + EPS);
    }
}

__global__ __launch_bounds__(256) void cm_k(float* __restrict__ out, float* __restrict__ ws,
                                            const float* __restrict__ m,
                                            const float* __restrict__ lnw,
                                            const float* __restrict__ lnb)
{
    const float* stats = ws + WS_ST_OFF;
    const int blk = blockIdx.x;
    const int b = blk >> 10;
    const int idx = (blk & 1023) * 256 + threadIdx.x;
    const size_t e = (size_t)b * CHB + idx;
    const float mu   = stats[80 + b];
    const float rstd = stats[88 + b];
    const float z  = ws[WS_Z_OFF + e];
    const float gi = gate_ptr(out, ws, 1)[e];
    const float gg = gate_ptr(out, ws, 2)[e];
    const float ip = gate_ptr(out, ws, 3)[e];
    const float gp = gate_ptr(out, ws, 4)[e];
    const float fp = gate_ptr(out, ws, 5)[e];
    const float c  = gi * gg + (z - mu) * rstd * lnw[idx] + lnb[idx];
    const float mn = ip * gp + fp * m[e];
    out[(size_t)4 * GATE_SZ + e] = c;
    out[(size_t)5 * GATE_SZ + e] = mn;
}

// ---- h_new = o * tanh(v) ----
__global__ __launch_bounds__(256) void hnew_elem_k(const float* __restrict__ o,
                                                   const float* __restrict__ v,
                                                   float* __restrict__ hn)
{
    const size_t i = (size_t)blockIdx.x * 256 + threadIdx.x;   // float4 idx, GATE_SZ/4 total
    float4 ov = ((const float4*)o)[i], vv = ((const float4*)v)[i];
    float4 r;
    r.x = ov.x * tanhf(vv.x); r.y = ov.y * tanhf(vv.y);
    r.z = ov.z * tanhf(vv.z); r.w = ov.w * tanhf(vv.w);
    ((float4*)hn)[i] = r;
}

// ---- c_history_new[0:4] = c_history[1:5] ----
__global__ __launch_bounds__(256) void hist_copy_k(const float* __restrict__ chist,
                                                   float* __restrict__ out)
{
    const size_t i = (size_t)blockIdx.x * 256 + threadIdx.x;
    const float4* src = (const float4*)(chist + GATE_SZ);
    float4* dst = (float4*)out;
    dst[i] = src[i];
}

extern "C" void kernel_launch(void* const* d_in, const int* in_sizes, int n_in,
                              void* d_out, int out_size, void* d_ws, size_t ws_size,
                              hipStream_t stream)
{
    const float* x    = (const float*)d_in[0];
    const float* ch   = (const float*)d_in[1];
    const float* m    = (const float*)d_in[2];
    const float* h    = (const float*)d_in[3];
    const float* Wx   = (const float*)d_in[4];
    const float* bx   = (const float*)d_in[5];
    const float* Wh   = (const float*)d_in[6];
    const float* bh   = (const float*)d_in[7];
    const float* w111 = (const float*)d_in[8];
    const float* b111 = (const float*)d_in[9];
    const float* lnw  = (const float*)d_in[10];
    const float* lnb  = (const float*)d_in[11];
    float* out = (float*)d_out;
    float* ws  = (float*)d_ws;

    // Scratch placement in DEAD d_out slots (ws stays within the proven
    // 4*GATE_SZ+128-float footprint):
    //   slot 4: XH (6 MB) — dead after conv_mfma MODE 0; start reused for LN4
    //           partials (64 KB) by recall_k; slot rewritten by cm_k with c.
    //   slot 5: A7 (2.2 MB) — dead after conv_mfma MODE 0; rewritten by cm_k.
    //   slot 6: XM (6 MB) + Ao/A111 (0.46 MB) — dead until hnew writes h_new.
    u16* XH   = (u16*)(out + (size_t)4 * GATE_SZ);
    u16* A7   = (u16*)(out + (size_t)5 * GATE_SZ);
    u16* XM   = (u16*)(out + (size_t)6 * GATE_SZ);
    u16* Ao   = XM + (size_t)BATCH * 4096 * 96;      // behind XM, same slot
    u16* A111 = Ao + (size_t)NO;
    u16* PCM  = (u16*)(ws + WS_Z_OFF);               // reuses Z region after cm_k
    float* part  = out + (size_t)4 * GATE_SZ;        // 16384 floats, dead XH region
    float* stats = ws + WS_ST_OFF;

    hipMemsetAsync(stats, 0, 128 * sizeof(float), stream);
    pack_w_k<<<(N7 + NO + N1 + 255) / 256, 256, 0, stream>>>(Wx, Wh, w111, A7, Ao, A111);
    pack_xhm_k<<<512, 256, 0, stream>>>(x, h, m, XH, XM);

    conv_mfma_k<96, 27, 2, 0><<<896, 256, 0, stream>>>(XH, XM, A7, bx, bh, nullptr, out, ws);
    ln3_act_k<<<3072, 256, 0, stream>>>(out, ws, 0);                 // gates 0..5

    scores_k<<<BATCH * TAU * 8, 256, 0, stream>>>(out, ch, stats);   // r = gate 0
    softmax_k<<<1, 64, 0, stream>>>(stats);
    recall_k<<<8192, 256, 0, stream>>>(ch, ws, part);
    ln4_stats_k<<<8, 256, 0, stream>>>(part, stats);
    cm_k<<<8192, 256, 0, stream>>>(out, ws, m, lnw, lnb);

    pack_pcm_k<<<512, 256, 0, stream>>>(out + (size_t)4 * GATE_SZ, out + (size_t)5 * GATE_SZ, PCM);
    conv_mfma_k<128, 27, 1, 1><<<256, 256, 0, stream>>>(PCM, nullptr, Ao, nullptr, bh, nullptr, out, ws);
    ln3_act_k<<<512, 256, 0, stream>>>(out, ws, 6);                  // gate 6 (o)
    conv_mfma_k<128, 1, 1, 2><<<256, 256, 0, stream>>>(PCM, nullptr, A111, nullptr, nullptr, b111, out, ws);

    hnew_elem_k<<<GATE_SZ / 1024, 256, 0, stream>>>(ws + (size_t)2 * GATE_SZ, ws, out + (size_t)6 * GATE_SZ);
    hist_copy_k<<<8192, 256, 0, stream>>>(ch, out);
}

// Round 5
// 439.894 us; speedup vs baseline: 6.3282x; 1.0432x over previous
//
#include <hip/hip_runtime.h>
#include <hip/hip_bf16.h>
#include <math.h>

// Problem constants
#define BATCH 8
#define CIN 16
#define HID 64
#define S2 1024            // 32*32
#define SP 4096            // 4*32*32 spatial elems per channel
#define CHB 262144         // HID*SP per batch
#define TAU 5
#define GATE_SZ 2097152    // BATCH*CHB floats = one gate buffer
#define EPS 1e-5f

// ws layout (floats): [0..3*GATE_SZ) = u4,u5,u6 ; [3G) Z ; [4G) stats(128 floats).
// Weight packs + PCM live in dead d_out slots (see kernel_launch).
#define WS_Z_OFF   ((size_t)3 * GATE_SZ)
#define WS_ST_OFF  ((size_t)4 * GATE_SZ)
// stats: scores[0..39] (l*8+b), attn[40..79], ln4 mu[80..87], ln4 rstd[88..95]

typedef unsigned short u16;
typedef __attribute__((ext_vector_type(8))) short  short8;
typedef __attribute__((ext_vector_type(8))) u16    ushort8;
typedef __attribute__((ext_vector_type(4))) float  f32x4;

#define N7 (7*27*64*96)
#define NO (27*64*128)
#define N1 (64*128)

__device__ __forceinline__ u16 f2b(float v) {
    __hip_bfloat16 h = __float2bfloat16(v);
    u16 r; __builtin_memcpy(&r, &h, 2); return r;
}

__device__ __forceinline__ float* gate_ptr(float* out, float* ws, int g) {
    return (g < 4) ? (out + (size_t)g * GATE_SZ) : (ws + (size_t)(g - 4) * GATE_SZ);
}

// ---- weight pack: A7[g][tap][oc][96], Ao[tap][oc][128], A111[oc][128] (bf16) ----
__global__ __launch_bounds__(256) void pack_w_k(const float* __restrict__ Wx,
                                                const float* __restrict__ Wh,
                                                const float* __restrict__ w111,
                                                u16* __restrict__ A7, u16* __restrict__ Ao,
                                                u16* __restrict__ A111)
{
    const int idx = blockIdx.x * 256 + threadIdx.x;
    if (idx < N7) {
        const int k = idx % 96, oc = (idx / 96) % 64, tap = (idx / (96*64)) % 27, g = idx / (96*64*27);
        float v = 0.f;
        if (k < 16)      v = Wx[((size_t)(g*64 + oc)*16 + k)      * 27 + tap];
        else if (k < 80) v = Wh[((size_t)(g*64 + oc)*64 + (k-16)) * 27 + tap];
        A7[idx] = f2b(v);
    } else if (idx < N7 + NO) {
        const int j = idx - N7;
        const int k = j % 128, oc = (j / 128) % 64, tap = j / (128*64);
        float v = (k < 64) ? Wh[((size_t)(7*64 + oc)*64 + k)      * 27 + tap]
                           : Wh[((size_t)(8*64 + oc)*64 + (k-64)) * 27 + tap];
        Ao[j] = f2b(v);
    } else if (idx < N7 + NO + N1) {
        const int j = idx - N7 - NO;
        A111[j] = f2b(w111[j]);
    }
}

// ---- input pack: XH[b][4096][96], XM[b][4096][96] (bf16, ch-minor) ----
__global__ __launch_bounds__(256) void pack_xhm_k(const float* __restrict__ x,
                                                  const float* __restrict__ h,
                                                  const float* __restrict__ m,
                                                  u16* __restrict__ XH, u16* __restrict__ XM)
{
    __shared__ float t[144][65];
    const int bi = blockIdx.x, b = bi >> 6, s0 = (bi & 63) << 6;
    for (int i = threadIdx.x; i < 144*64; i += 256) {
        const int row = i >> 6, sc = i & 63;
        float v;
        if (row < 16)      v = x[((size_t)b*16 + row)      * SP + s0 + sc];
        else if (row < 80) v = h[((size_t)b*64 + (row-16)) * SP + s0 + sc];
        else               v = m[((size_t)b*64 + (row-80)) * SP + s0 + sc];
        t[row][sc] = v;
    }
    __syncthreads();
    for (int j = threadIdx.x; j < 64*96; j += 256) {
        const int s = j / 96, ch = j % 96;
        const size_t o = ((size_t)b*4096 + s0 + s) * 96 + ch;
        XH[o] = f2b(ch < 80 ? t[ch][s] : 0.f);
        XM[o] = f2b(ch < 16 ? t[ch][s] : (ch < 80 ? t[ch + 64][s] : 0.f));
    }
}

// ---- implicit-GEMM conv via MFMA 16x16x32 bf16, software-pipelined tap loop ----
// MODE 0: 7 gate convs (K=96, 27 taps, X = XH or XM per gate, bias bx+bh, write)
// MODE 1: o-gate state conv (K=128 split in 2 halves, 27 taps, X=PCM, atomicAdd into ws u6)
// MODE 2: 1x1x1 conv (K=128, 1 tap, X=PCM, bias b111, write v into ws slot 0)
template<int KCH, int TAPS, int NR, int MODE>
__global__ __launch_bounds__(256, 3) void conv_mfma_k(
    const u16* __restrict__ XA, const u16* __restrict__ XB,
    const u16* __restrict__ Apack,
    const float* __restrict__ bxp, const float* __restrict__ bhp,
    const float* __restrict__ b111,
    float* __restrict__ out, float* __restrict__ ws)
{
    constexpr int YT   = NR + 2;        // y rows in tile (with halo)
    constexpr int ROWS = 4 * YT * 34;   // t * y * x(with halo)
    constexpr int PADK = 40;            // 32 ch + pad (80B rows, 16B-aligned)
    __shared__ __align__(16) u16 xs[ROWS * PADK];

    const int bi = blockIdx.x;
    int g = 0, b, y0, kh = 0, kc_lo = 0, kc_hi = KCH / 32;
    const u16* X; const u16* Ag; float* outp;
    if (MODE == 0) {
        constexpr int YB = 32 / NR;
        g  = bi / (8 * YB);
        b  = (bi / YB) % 8;
        y0 = (bi % YB) * NR;
        X  = (g >= 3 && g <= 5) ? XB : XA;
        Ag = Apack + (size_t)g * TAPS * 64 * KCH;
        outp = gate_ptr(out, ws, g) + (size_t)b * CHB;
    } else if (MODE == 1) {
        kh = bi >> 8; b = (bi >> 5) & 7; y0 = bi & 31;
        kc_lo = kh * 2; kc_hi = kc_lo + 2;
        X = XA; Ag = Apack;
        outp = ws + (size_t)2 * GATE_SZ + (size_t)b * CHB;
    } else {
        b = bi >> 5; y0 = bi & 31;
        X = XA; Ag = Apack;
        outp = ws + (size_t)b * CHB;
    }
    const u16* Xb = X + (size_t)b * 4096 * KCH;

    const int tid  = threadIdx.x;
    const int w    = tid >> 6;          // wave = output t-plane
    const int lane = tid & 63;
    const int xn   = lane & 15, quad = lane >> 4;

    f32x4 acc[4][2 * NR] = {};

    for (int kc = kc_lo; kc < kc_hi; ++kc) {
        if (kc != kc_lo) __syncthreads();
        // stage 32-channel slab of the (t, y-halo, x-halo) tile into LDS
        for (int cix = tid; cix < ROWS * 4; cix += 256) {
            const int r = cix >> 2, sub = cix & 3;
            const int t = r / (YT * 34), rem = r % (YT * 34);
            const int yy = rem / 34, xx = rem % 34;
            const int gy = y0 + yy - 1, gx = xx - 1;
            ushort8 v = {0, 0, 0, 0, 0, 0, 0, 0};
            if ((unsigned)gy < 32u && (unsigned)gx < 32u)
                v = *(const ushort8*)&Xb[(size_t)(t * 1024 + gy * 32 + gx) * KCH + kc * 32 + sub * 8];
            *(ushort8*)&xs[r * PADK + sub * 8] = v;
        }
        __syncthreads();

        auto load_a = [&](short8* a, int tap) {
            #pragma unroll
            for (int mt = 0; mt < 4; ++mt)
                a[mt] = *(const short8*)&Ag[(size_t)(tap * 64 + mt * 16 + xn) * KCH + kc * 32 + quad * 8];
        };
        auto load_b = [&](short8* bf, int tap) {
            int kd, ky, kx;
            if (TAPS == 27) { kd = tap / 9; ky = (tap / 3) % 3; kx = tap % 3; }
            else            { kd = 1; ky = 1; kx = 1; }
            const int tin = w + kd - 1;
            #pragma unroll
            for (int nt = 0; nt < 2 * NR; ++nt) {
                const int ysub = nt >> 1, xh = nt & 1;
                bf[nt] = *(const short8*)
                    &xs[((tin * YT + ysub + ky) * 34 + xh * 16 + xn + kx) * PADK + quad * 8];
            }
        };
        auto do_mfma = [&](short8* a, short8* bf) {
            #pragma unroll
            for (int nt = 0; nt < 2 * NR; ++nt)
                #pragma unroll
                for (int mt = 0; mt < 4; ++mt)
                    acc[mt][nt] = __builtin_amdgcn_mfma_f32_16x16x32_bf16(a[mt], bf[nt], acc[mt][nt], 0, 0, 0);
        };

        if (TAPS == 27) {
            // valid taps form a contiguous range per wave (t-plane)
            const int tap_lo = (w == 0) ? 9 : 0;
            const int tap_hi = (w == 3) ? 18 : 27;
            short8 a0[4], b0[2 * NR], a1[4], b1[2 * NR];
            load_a(a0, tap_lo); load_b(b0, tap_lo);
            int tap = tap_lo;
            for (; tap + 2 <= tap_hi; tap += 2) {
                load_a(a1, tap + 1); load_b(b1, tap + 1);   // prefetch tap+1
                do_mfma(a0, b0);                            // compute tap
                if (tap + 2 < tap_hi) { load_a(a0, tap + 2); load_b(b0, tap + 2); }
                do_mfma(a1, b1);                            // compute tap+1
            }
            if (tap < tap_hi) do_mfma(a0, b0);              // odd tail
        } else {
            short8 a0[4], b0[2 * NR];
            load_a(a0, 0); load_b(b0, 0);
            do_mfma(a0, b0);
        }
    }

    // epilogue: C/D layout col=lane&15, row=quad*4+reg
    #pragma unroll
    for (int mt = 0; mt < 4; ++mt)
    #pragma unroll
    for (int nt = 0; nt < 2 * NR; ++nt) {
        const int ysub = nt >> 1, xh = nt & 1;
        const int sp = w * 1024 + (y0 + ysub) * 32 + xh * 16 + xn;
        #pragma unroll
        for (int reg = 0; reg < 4; ++reg) {
            const int oc = mt * 16 + quad * 4 + reg;
            float bias;
            if (MODE == 0)      bias = bxp[g * 64 + oc] + bhp[g * 64 + oc];
            else if (MODE == 1) bias = (kh == 0) ? (bhp[7 * 64 + oc] + bhp[8 * 64 + oc]) : 0.f;
            else                bias = b111[oc];
            const float vv = acc[mt][nt][reg] + bias;
            float* p = outp + (size_t)oc * SP + sp;
            if (MODE == 1) atomicAdd(p, vv); else *p = vv;
        }
    }
}

// ---- LayerNorm over 4096 spatial elems of one (gate,b,c), in place, + activation ----
__global__ __launch_bounds__(256) void ln3_act_k(float* __restrict__ out,
                                                 float* __restrict__ ws, int gate0)
{
    const int blk = blockIdx.x;
    const int g = gate0 + (blk >> 9);
    float* p = gate_ptr(out, ws, g) + (size_t)(blk & 511) * SP;
    const int tid = threadIdx.x;

    float s = 0.f, s2 = 0.f;
    for (int k = tid; k < SP; k += 256) { float v = p[k]; s += v; s2 += v * v; }
    #pragma unroll
    for (int off = 32; off > 0; off >>= 1) { s += __shfl_down(s, off); s2 += __shfl_down(s2, off); }
    __shared__ float rs[4], rs2[4], stat[2];
    if ((tid & 63) == 0) { rs[tid >> 6] = s; rs2[tid >> 6] = s2; }
    __syncthreads();
    if (tid == 0) {
        float S  = rs[0] + rs[1] + rs[2] + rs[3];
        float Sq = rs2[0] + rs2[1] + rs2[2] + rs2[3];
        float mu  = S * (1.f / SP);
        float var = Sq * (1.f / SP) - mu * mu;
        stat[0] = mu; stat[1] = rsqrtf(var + EPS);
    }
    __syncthreads();
    const float mu = stat[0], r = stat[1];
    const bool use_tanh = (g == 2 || g == 4);
    for (int k = tid; k < SP; k += 256) {
        float v = (p[k] - mu) * r;
        p[k] = use_tanh ? tanhf(v) : 1.f / (1.f + expf(-v));
    }
}

// ---- attention scores / softmax(dim=0) ----
__global__ __launch_bounds__(256) void scores_k(const float* __restrict__ r,
                                                const float* __restrict__ chist,
                                                float* __restrict__ stats)
{
    const int blk = blockIdx.x;
    const int chunk = blk & 7;
    const int bl = blk >> 3;
    const int l = bl % 5, b = bl / 5;
    const float* rp = r + (size_t)b * CHB;
    const float* cp = chist + (size_t)(l * BATCH + b) * CHB;
    float s = 0.f;
    const int lo = chunk * (CHB / 8);
    for (int k = lo + threadIdx.x; k < lo + CHB / 8; k += 256) s += rp[k] * cp[k];
    #pragma unroll
    for (int off = 32; off > 0; off >>= 1) s += __shfl_down(s, off);
    __shared__ float rsh[4];
    if ((threadIdx.x & 63) == 0) rsh[threadIdx.x >> 6] = s;
    __syncthreads();
    if (threadIdx.x == 0)
        atomicAdd(&stats[l * 8 + b], (rsh[0] + rsh[1] + rsh[2] + rsh[3]) * (1.f / 64.f));
}

__global__ void softmax_k(float* __restrict__ stats)
{
    int l = threadIdx.x;
    if (l < TAU) {
        float mx = -1e30f;
        for (int b = 0; b < BATCH; ++b) mx = fmaxf(mx, stats[l * 8 + b]);
        float e[BATCH]; float sum = 0.f;
        for (int b = 0; b < BATCH; ++b) { e[b] = expf(stats[l * 8 + b] - mx); sum += e[b]; }
        for (int b = 0; b < BATCH; ++b) stats[40 + l * 8 + b] = e[b] / sum;
    }
}

// ---- z = chist[4,b] + sum_l attn[b,l]*chist[l,b]; per-block partials (NO atomics) ----
__global__ __launch_bounds__(256) void recall_k(const float* __restrict__ chist,
                                                float* __restrict__ ws,
                                                float* __restrict__ part)
{
    const float* stats = ws + WS_ST_OFF;
    const int blk = blockIdx.x;
    const int b = blk >> 10;
    const int idx = (blk & 1023) * 256 + threadIdx.x;
    const float a0 = stats[40 +  0 + b], a1 = stats[40 +  8 + b], a2 = stats[40 + 16 + b];
    const float a3 = stats[40 + 24 + b], a4 = stats[40 + 32 + b];
    const size_t e = (size_t)b * CHB + idx;
    const size_t LB = (size_t)BATCH * CHB;
    float z = chist[4 * LB + e] * (1.f + a4)
            + a0 * chist[0 * LB + e] + a1 * chist[1 * LB + e]
            + a2 * chist[2 * LB + e] + a3 * chist[3 * LB + e];
    ws[WS_Z_OFF + e] = z;

    float s = z, s2 = z * z;
    #pragma unroll
    for (int off = 32; off > 0; off >>= 1) { s += __shfl_down(s, off); s2 += __shfl_down(s2, off); }
    __shared__ float rs[4], rs2[4];
    if ((threadIdx.x & 63) == 0) { rs[threadIdx.x >> 6] = s; rs2[threadIdx.x >> 6] = s2; }
    __syncthreads();
    if (threadIdx.x == 0) {
        part[blk]        = rs[0] + rs[1] + rs[2] + rs[3];
        part[8192 + blk] = rs2[0] + rs2[1] + rs2[2] + rs2[3];
    }
}

// ---- reduce 1024 partials per batch -> stats[80+b]=mu, stats[88+b]=rstd ----
__global__ __launch_bounds__(256) void ln4_stats_k(const float* __restrict__ part,
                                                   float* __restrict__ stats)
{
    const int b = blockIdx.x;
    float s = 0.f, s2 = 0.f;
    for (int j = threadIdx.x; j < 1024; j += 256) {
        s  += part[b * 1024 + j];
        s2 += part[8192 + b * 1024 + j];
    }
    #pragma unroll
    for (int off = 32; off > 0; off >>= 1) { s += __shfl_down(s, off); s2 += __shfl_down(s2, off); }
    __shared__ float rs[4], rs2[4];
    if ((threadIdx.x & 63) == 0) { rs[threadIdx.x >> 6] = s; rs2[threadIdx.x >> 6] = s2; }
    __syncthreads();
    if (threadIdx.x == 0) {
        float S  = rs[0] + rs[1] + rs[2] + rs[3];
        float Sq = rs2[0] + rs2[1] + rs2[2] + rs2[3];
        float mu  = S * (1.f / CHB);
        float var = Sq * (1.f / CHB) - mu * mu;
        stats[80 + b] = mu;
        stats[88 + b] = rsqrtf(var + EPS);
    }
}

// ---- fused: c = i*g + LN4(z)*lnw + lnb ; m_new = i'*g' + f'*m ; PCM bf16 pack ----
// block = (b, 64-sp chunk); writes out slots 4,5 (coalesced) + PCM via LDS transpose.
__global__ __launch_bounds__(256) void cm_pcm_k(float* __restrict__ out, float* __restrict__ ws,
                                                const float* __restrict__ m,
                                                const float* __restrict__ lnw,
                                                const float* __restrict__ lnb,
                                                u16* __restrict__ PCM)
{
    __shared__ __align__(16) u16 tl[64][136];   // [sp][128 ch + pad], 16B-aligned rows
    const int bi = blockIdx.x;
    const int b = bi >> 6;
    const int s0 = (bi & 63) << 6;
    const float* stats = ws + WS_ST_OFF;
    const float mu = stats[80 + b], rstd = stats[88 + b];

    for (int i = threadIdx.x; i < 1024; i += 256) {       // 64ch x 16 float4
        const int chn = i >> 4;
        const int sp4 = (i & 15) << 2;
        const size_t e = (size_t)b * CHB + (size_t)chn * SP + s0 + sp4;
        const size_t le = (size_t)chn * SP + s0 + sp4;
        float4 z  = *(const float4*)&ws[WS_Z_OFF + e];
        float4 gi = *(const float4*)&gate_ptr(out, ws, 1)[e];
        float4 gg = *(const float4*)&gate_ptr(out, ws, 2)[e];
        float4 ip = *(const float4*)&gate_ptr(out, ws, 3)[e];
        float4 gp = *(const float4*)&gate_ptr(out, ws, 4)[e];
        float4 fp = *(const float4*)&gate_ptr(out, ws, 5)[e];
        float4 mm = *(const float4*)&m[e];
        float4 lw = *(const float4*)&lnw[le];
        float4 lb = *(const float4*)&lnb[le];
        float4 c, mn;
        c.x = gi.x * gg.x + (z.x - mu) * rstd * lw.x + lb.x;
        c.y = gi.y * gg.y + (z.y - mu) * rstd * lw.y + lb.y;
        c.z = gi.z * gg.z + (z.z - mu) * rstd * lw.z + lb.z;
        c.w = gi.w * gg.w + (z.w - mu) * rstd * lw.w + lb.w;
        mn.x = ip.x * gp.x + fp.x * mm.x;
        mn.y = ip.y * gp.y + fp.y * mm.y;
        mn.z = ip.z * gp.z + fp.z * mm.z;
        mn.w = ip.w * gp.w + fp.w * mm.w;
        *(float4*)&out[(size_t)4 * GATE_SZ + e] = c;
        *(float4*)&out[(size_t)5 * GATE_SZ + e] = mn;
        const float cc[4] = {c.x, c.y, c.z, c.w};
        const float mm2[4] = {mn.x, mn.y, mn.z, mn.w};
        #pragma unroll
        for (int k = 0; k < 4; ++k) {
            tl[sp4 + k][chn]      = f2b(cc[k]);
            tl[sp4 + k][64 + chn] = f2b(mm2[k]);
        }
    }
    __syncthreads();
    for (int j = threadIdx.x; j < 1024; j += 256) {       // 64 s x 16 ushort8
        const int s = j >> 4, c8 = (j & 15) << 3;
        ushort8 v = *(const ushort8*)&tl[s][c8];
        *(ushort8*)&PCM[((size_t)b * 4096 + s0 + s) * 128 + c8] = v;
    }
}

// ---- h_new = o * tanh(v) ----
__global__ __launch_bounds__(256) void hnew_elem_k(const float* __restrict__ o,
                                                   const float* __restrict__ v,
                                                   float* __restrict__ hn)
{
    const size_t i = (size_t)blockIdx.x * 256 + threadIdx.x;   // float4 idx, GATE_SZ/4 total
    float4 ov = ((const float4*)o)[i], vv = ((const float4*)v)[i];
    float4 r;
    r.x = ov.x * tanhf(vv.x); r.y = ov.y * tanhf(vv.y);
    r.z = ov.z * tanhf(vv.z); r.w = ov.w * tanhf(vv.w);
    ((float4*)hn)[i] = r;
}

// ---- c_history_new[0:4] = c_history[1:5] ----
__global__ __launch_bounds__(256) void hist_copy_k(const float* __restrict__ chist,
                                                   float* __restrict__ out)
{
    const size_t i = (size_t)blockIdx.x * 256 + threadIdx.x;
    const float4* src = (const float4*)(chist + GATE_SZ);
    float4* dst = (float4*)out;
    dst[i] = src[i];
}

extern "C" void kernel_launch(void* const* d_in, const int* in_sizes, int n_in,
                              void* d_out, int out_size, void* d_ws, size_t ws_size,
                              hipStream_t stream)
{
    const float* x    = (const float*)d_in[0];
    const float* ch   = (const float*)d_in[1];
    const float* m    = (const float*)d_in[2];
    const float* h    = (const float*)d_in[3];
    const float* Wx   = (const float*)d_in[4];
    const float* bx   = (const float*)d_in[5];
    const float* Wh   = (const float*)d_in[6];
    const float* bh   = (const float*)d_in[7];
    const float* w111 = (const float*)d_in[8];
    const float* b111 = (const float*)d_in[9];
    const float* lnw  = (const float*)d_in[10];
    const float* lnb  = (const float*)d_in[11];
    float* out = (float*)d_out;
    float* ws  = (float*)d_ws;

    // Scratch placement in DEAD d_out slots (ws stays within the proven
    // 4*GATE_SZ+128-float footprint):
    //   slot 0: u0 (r) until scores_k; then PCM (8 MB) written by cm_pcm_k,
    //           read by conv MODE 1/2, finally overwritten by hist_copy.
    //   slot 4: XH (6 MB) dead after MODE 0; head reused for LN4 partials
    //           (64 KB) by recall_k; slot rewritten by cm_pcm_k with c.
    //   slot 5: A7 (2.2 MB) dead after MODE 0; rewritten by cm_pcm_k (m_new).
    //   slot 6: XM (6 MB) + Ao/A111 (0.46 MB) — dead until hnew writes h_new.
    u16* XH   = (u16*)(out + (size_t)4 * GATE_SZ);
    u16* A7   = (u16*)(out + (size_t)5 * GATE_SZ);
    u16* XM   = (u16*)(out + (size_t)6 * GATE_SZ);
    u16* Ao   = XM + (size_t)BATCH * 4096 * 96;      // behind XM, same slot
    u16* A111 = Ao + (size_t)NO;
    u16* PCM  = (u16*)out;                           // slot 0 (dead after scores_k)
    float* part  = out + (size_t)4 * GATE_SZ;        // 16384 floats, dead XH region
    float* stats = ws + WS_ST_OFF;

    hipMemsetAsync(stats, 0, 128 * sizeof(float), stream);
    pack_w_k<<<(N7 + NO + N1 + 255) / 256, 256, 0, stream>>>(Wx, Wh, w111, A7, Ao, A111);
    pack_xhm_k<<<512, 256, 0, stream>>>(x, h, m, XH, XM);

    conv_mfma_k<96, 27, 2, 0><<<896, 256, 0, stream>>>(XH, XM, A7, bx, bh, nullptr, out, ws);
    ln3_act_k<<<3072, 256, 0, stream>>>(out, ws, 0);                 // gates 0..5

    scores_k<<<BATCH * TAU * 8, 256, 0, stream>>>(out, ch, stats);   // r = gate 0
    softmax_k<<<1, 64, 0, stream>>>(stats);
    recall_k<<<8192, 256, 0, stream>>>(ch, ws, part);
    ln4_stats_k<<<8, 256, 0, stream>>>(part, stats);
    cm_pcm_k<<<512, 256, 0, stream>>>(out, ws, m, lnw, lnb, PCM);

    conv_mfma_k<128, 27, 1, 1><<<512, 256, 0, stream>>>(PCM, nullptr, Ao, nullptr, bh, nullptr, out, ws);
    ln3_act_k<<<512, 256, 0, stream>>>(out, ws, 6);                  // gate 6 (o)
    conv_mfma_k<128, 1, 1, 2><<<256, 256, 0, stream>>>(PCM, nullptr, A111, nullptr, nullptr, b111, out, ws);

    hnew_elem_k<<<GATE_SZ / 1024, 256, 0, stream>>>(ws + (size_t)2 * GATE_SZ, ws, out + (size_t)6 * GATE_SZ);
    hist_copy_k<<<8192, 256, 0, stream>>>(ch, out);
}